// Round 1
// baseline (602.745 us; speedup 1.0000x reference)
//
#include <hip/hip_runtime.h>
#include <hip/hip_bf16.h>

typedef __bf16 bf16x8 __attribute__((ext_vector_type(8)));
typedef float f32x4 __attribute__((ext_vector_type(4)));

#define MFMA16 __builtin_amdgcn_mfma_f32_16x16x32_bf16

__device__ __forceinline__ unsigned short f2b(float f) {
  return __builtin_bit_cast(unsigned short, (__bf16)f);
}

// ---------------------------------------------------------------------------
// Kernel 1: XT[b][n][c] = (bf16) x[b][c][n]   (tiled transpose + cast)
// ---------------------------------------------------------------------------
__global__ __launch_bounds__(256) void k_transpose(const float* __restrict__ x,
                                                   unsigned short* __restrict__ xt) {
  __shared__ float tile[64][65];  // +1 pad: conflict-free transposed reads
  const int nt = blockIdx.x, ct = blockIdx.y, b = blockIdx.z;
  const int tid = threadIdx.x;
  const int j4 = (tid & 15) * 4, r0 = tid >> 4;
  const float* src = x + ((size_t)(b * 256 + ct * 64) * 4096) + nt * 64;
#pragma unroll
  for (int p = 0; p < 4; ++p) {
    int r = r0 + p * 16;
    float4 v = *reinterpret_cast<const float4*>(src + (size_t)r * 4096 + j4);
    tile[r][j4] = v.x; tile[r][j4 + 1] = v.y; tile[r][j4 + 2] = v.z; tile[r][j4 + 3] = v.w;
  }
  __syncthreads();
  unsigned short* dst = xt + ((size_t)(b * 4096 + nt * 64)) * 256 + ct * 64;
#pragma unroll
  for (int p = 0; p < 4; ++p) {
    int r = r0 + p * 16;
    ushort4 o;
    o.x = f2b(tile[j4][r]);
    o.y = f2b(tile[j4 + 1][r]);
    o.z = f2b(tile[j4 + 2][r]);
    o.w = f2b(tile[j4 + 3][r]);
    *reinterpret_cast<ushort4*>(dst + (size_t)r * 256 + j4) = o;
  }
}

// ---------------------------------------------------------------------------
// Kernel 2: projections.  blockIdx.y = mode (0:Q=Wa, 1:K=Wb, 2:V=Wm+BN)
//   Q,K written [b][n][c] row-major bf16 ; V written [b][c][m] bf16.
//   D[i=n][j=o] = sum_c XT[n][c] * W[o][c]   (A = XT rows, B = W rows, both
//   contiguous-K 16B fragment loads, no LDS needed for operands)
// ---------------------------------------------------------------------------
__global__ __launch_bounds__(256) void k_qkv(
    const unsigned short* __restrict__ xt,
    const float* __restrict__ Wa, const float* __restrict__ ba,
    const float* __restrict__ Wb, const float* __restrict__ bb,
    const float* __restrict__ Wm, const float* __restrict__ bm,
    const float* __restrict__ gamma, const float* __restrict__ beta,
    const float* __restrict__ rmean, const float* __restrict__ rvar,
    unsigned short* __restrict__ Q, unsigned short* __restrict__ K,
    unsigned short* __restrict__ V) {
  const int nt = blockIdx.x, mode = blockIdx.y, b = blockIdx.z;
  const int tid = threadIdx.x, w = tid >> 6, l = tid & 63;
  const int li = l & 15, lk = l >> 4;
  const float* W = (mode == 0) ? Wa : (mode == 1) ? Wb : Wm;
  const int row = nt * 64 + w * 16 + li;  // n index for this lane's A-fragment
  const unsigned short* arow = xt + ((size_t)b * 4096 + row) * 256;
  bf16x8 af[8];
#pragma unroll
  for (int kk = 0; kk < 8; ++kk)
    af[kk] = *reinterpret_cast<const bf16x8*>(arow + kk * 32 + lk * 8);
  f32x4 zero = {0.f, 0.f, 0.f, 0.f};
  f32x4 acc[16];
#pragma unroll
  for (int i = 0; i < 16; ++i) acc[i] = zero;
#pragma unroll
  for (int kk = 0; kk < 8; ++kk) {
#pragma unroll
    for (int of = 0; of < 16; ++of) {
      const float* wrow = W + (size_t)(of * 16 + li) * 256 + kk * 32 + lk * 8;
      float4 w0 = *reinterpret_cast<const float4*>(wrow);
      float4 w1 = *reinterpret_cast<const float4*>(wrow + 4);
      bf16x8 bfv;
      bfv[0] = (__bf16)w0.x; bfv[1] = (__bf16)w0.y; bfv[2] = (__bf16)w0.z; bfv[3] = (__bf16)w0.w;
      bfv[4] = (__bf16)w1.x; bfv[5] = (__bf16)w1.y; bfv[6] = (__bf16)w1.z; bfv[7] = (__bf16)w1.w;
      acc[of] = MFMA16(af[kk], bfv, acc[of], 0, 0, 0);
    }
  }
  // D layout: col = lane&15 (= o within fragment), row = (lane>>4)*4 + reg (= n)
  if (mode < 2) {
    const float* bias = (mode == 0) ? ba : bb;
    unsigned short* out = ((mode == 0) ? Q : K) + ((size_t)b * 4096 + nt * 64 + w * 16) * 256;
#pragma unroll
    for (int of = 0; of < 16; ++of) {
      int c = of * 16 + li;
      float bs = bias[c];
#pragma unroll
      for (int r = 0; r < 4; ++r)
        out[(size_t)(lk * 4 + r) * 256 + c] = f2b(acc[of][r] + bs);
    }
  } else {
    unsigned short* out = V + (size_t)b * 256 * 4096;
    const int n0 = nt * 64 + w * 16 + lk * 4;
#pragma unroll
    for (int of = 0; of < 16; ++of) {
      int c = of * 16 + li;
      float g = rsqrtf(rvar[c] + 1e-5f) * gamma[c];
      float sh = (bm[c] - rmean[c]) * g + beta[c];
      ushort4 o4;
      o4.x = f2b(acc[of][0] * g + sh);
      o4.y = f2b(acc[of][1] * g + sh);
      o4.z = f2b(acc[of][2] * g + sh);
      o4.w = f2b(acc[of][3] * g + sh);
      *reinterpret_cast<ushort4*>(out + (size_t)c * 4096 + n0) = o4;
    }
  }
}

// ---------------------------------------------------------------------------
// Kernel 3: flash attention + epilogue.  256 blocks (1/CU), 4 waves/block.
//   Each wave owns 16 query rows; block covers 64; iterates 64-key tiles.
// ---------------------------------------------------------------------------
__global__ __launch_bounds__(256) void k_attn(
    const unsigned short* __restrict__ Q, const unsigned short* __restrict__ K,
    const unsigned short* __restrict__ V, const float* __restrict__ feat,
    const float* __restrict__ alpha, float* __restrict__ out) {
  constexpr int KP = 264;  // K row pad: 2-way-only bank aliasing on b128 reads
  constexpr int VP = 72;   // V row pad
  constexpr int PP = 72;   // P row pad
  __shared__ unsigned short K_lds[64 * KP];
  __shared__ unsigned short V_lds[256 * VP];
  __shared__ unsigned short P_lds[4 * 16 * PP];
  const int blk = blockIdx.x;
  // XCD-aware swizzle: 2 XCDs per batch -> per-XCD K+V working set = 4MB = L2
  const int xcd = blk & 7;
  const int b = xcd >> 1;
  const int qt = ((blk >> 3) << 1) | (xcd & 1);
  const int tid = threadIdx.x, w = tid >> 6, l = tid & 63;
  const int li = l & 15, lk = l >> 4;
  const int q0 = qt * 64;
  const unsigned short* qp = Q + ((size_t)b * 4096 + q0 + w * 16 + li) * 256;
  bf16x8 qf[8];
#pragma unroll
  for (int kk = 0; kk < 8; ++kk)
    qf[kk] = *reinterpret_cast<const bf16x8*>(qp + kk * 32 + lk * 8);
  f32x4 zero = {0.f, 0.f, 0.f, 0.f};
  f32x4 acc[16];
#pragma unroll
  for (int i = 0; i < 16; ++i) acc[i] = zero;
  float mr[4] = {-1e30f, -1e30f, -1e30f, -1e30f};
  float lr[4] = {0.f, 0.f, 0.f, 0.f};

  for (int kt = 0; kt < 64; ++kt) {
    const int k0 = kt * 64;
    // stage K tile [64 keys][256 c] row-major
#pragma unroll
    for (int p = 0; p < 8; ++p) {
      int task = p * 256 + tid;
      int r = task >> 5, ch = task & 31;
      bf16x8 v = *reinterpret_cast<const bf16x8*>(K + ((size_t)b * 4096 + k0 + r) * 256 + ch * 8);
      *reinterpret_cast<bf16x8*>(&K_lds[r * KP + ch * 8]) = v;
    }
    // stage V tile [256 c][64 keys]
#pragma unroll
    for (int p = 0; p < 8; ++p) {
      int task = p * 256 + tid;
      int r = task >> 3, ch = task & 7;
      bf16x8 v = *reinterpret_cast<const bf16x8*>(V + ((size_t)b * 256 + r) * 4096 + k0 + ch * 8);
      *reinterpret_cast<bf16x8*>(&V_lds[r * VP + ch * 8]) = v;
    }
    __syncthreads();
    // S[16 n][64 m] = Q . K^T
    f32x4 s[4];
#pragma unroll
    for (int jf = 0; jf < 4; ++jf) s[jf] = zero;
#pragma unroll
    for (int kk = 0; kk < 8; ++kk) {
#pragma unroll
      for (int jf = 0; jf < 4; ++jf) {
        bf16x8 kf = *reinterpret_cast<const bf16x8*>(&K_lds[(jf * 16 + li) * KP + kk * 32 + lk * 8]);
        s[jf] = MFMA16(qf[kk], kf, s[jf], 0, 0, 0);
      }
    }
    // online softmax: row r (= n-local lk*4+r) spans the 16 lanes of this group
    float scale[4];
#pragma unroll
    for (int r = 0; r < 4; ++r) {
      float pm = fmaxf(fmaxf(s[0][r], s[1][r]), fmaxf(s[2][r], s[3][r]));
      pm = fmaxf(pm, __shfl_xor(pm, 1));
      pm = fmaxf(pm, __shfl_xor(pm, 2));
      pm = fmaxf(pm, __shfl_xor(pm, 4));
      pm = fmaxf(pm, __shfl_xor(pm, 8));
      float nm = fmaxf(mr[r], pm);
      scale[r] = __expf(mr[r] - nm);
      mr[r] = nm;
      float sum = 0.f;
#pragma unroll
      for (int jf = 0; jf < 4; ++jf) {
        float pv = __expf(s[jf][r] - nm);
        sum += pv;
        P_lds[(w * 16 + lk * 4 + r) * PP + jf * 16 + li] = f2b(pv);
      }
      sum += __shfl_xor(sum, 1);
      sum += __shfl_xor(sum, 2);
      sum += __shfl_xor(sum, 4);
      sum += __shfl_xor(sum, 8);
      lr[r] = lr[r] * scale[r] + sum;
    }
#pragma unroll
    for (int cf = 0; cf < 16; ++cf) {
#pragma unroll
      for (int r = 0; r < 4; ++r) acc[cf][r] *= scale[r];
    }
    __syncthreads();  // P_lds visible (and keeps waves phase-locked)
    // O[16 n][256 c] += P . V^T   (V_lds rows are channels: B[k=m][j=c])
#pragma unroll
    for (int ks = 0; ks < 2; ++ks) {
      bf16x8 pf = *reinterpret_cast<const bf16x8*>(&P_lds[(w * 16 + li) * PP + ks * 32 + lk * 8]);
#pragma unroll
      for (int cf = 0; cf < 16; ++cf) {
        bf16x8 vf = *reinterpret_cast<const bf16x8*>(&V_lds[(cf * 16 + li) * VP + ks * 32 + lk * 8]);
        acc[cf] = MFMA16(pf, vf, acc[cf], 0, 0, 0);
      }
    }
    __syncthreads();  // protect K_lds/V_lds before next stage
  }
  const float av = alpha[0];
  float rinv[4];
#pragma unroll
  for (int r = 0; r < 4; ++r) rinv[r] = av / lr[r];
  const int n0 = q0 + w * 16 + lk * 4;
#pragma unroll
  for (int cf = 0; cf < 16; ++cf) {
    int c = cf * 16 + li;
    size_t base = ((size_t)b * 256 + c) * 4096 + n0;
    float4 f4 = *reinterpret_cast<const float4*>(feat + base);
    float4 o4;
    o4.x = f4.x + acc[cf][0] * rinv[0];
    o4.y = f4.y + acc[cf][1] * rinv[1];
    o4.z = f4.z + acc[cf][2] * rinv[2];
    o4.w = f4.w + acc[cf][3] * rinv[3];
    *reinterpret_cast<float4*>(out + base) = o4;
  }
}

extern "C" void kernel_launch(void* const* d_in, const int* in_sizes, int n_in,
                              void* d_out, int out_size, void* d_ws, size_t ws_size,
                              hipStream_t stream) {
  const float* feat  = (const float*)d_in[0];
  const float* Wa    = (const float*)d_in[1];
  const float* ba    = (const float*)d_in[2];
  const float* Wb    = (const float*)d_in[3];
  const float* bb    = (const float*)d_in[4];
  const float* Wm    = (const float*)d_in[5];
  const float* bm    = (const float*)d_in[6];
  const float* gamma = (const float*)d_in[7];
  const float* beta  = (const float*)d_in[8];
  const float* rmean = (const float*)d_in[9];
  const float* rvar  = (const float*)d_in[10];
  const float* alpha = (const float*)d_in[11];
  float* out = (float*)d_out;
  char* ws = (char*)d_ws;
  unsigned short* XT = (unsigned short*)(ws);               // 8 MB  [B][N][C] bf16
  unsigned short* Qb = (unsigned short*)(ws + (8 << 20));   // 8 MB  [B][N][C] bf16
  unsigned short* Kb = (unsigned short*)(ws + (16 << 20));  // 8 MB  [B][N][C] bf16
  unsigned short* Vb = (unsigned short*)(ws + (24 << 20));  // 8 MB  [B][C][N] bf16

  dim3 g1(64, 4, 4);  // n-tiles, c-tiles, batch
  k_transpose<<<g1, 256, 0, stream>>>(feat, XT);
  dim3 g2(64, 3, 4);  // n-tiles, {Q,K,V}, batch
  k_qkv<<<g2, 256, 0, stream>>>(XT, Wa, ba, Wb, bb, Wm, bm, gamma, beta, rmean, rvar,
                                Qb, Kb, Vb);
  k_attn<<<dim3(256), dim3(256), 0, stream>>>(Qb, Kb, Vb, feat, alpha, out);
}

// Round 2
// 334.163 us; speedup vs baseline: 1.8037x; 1.8037x over previous
//
#include <hip/hip_runtime.h>
#include <hip/hip_bf16.h>

typedef __bf16 bf16x8 __attribute__((ext_vector_type(8)));
typedef float f32x4 __attribute__((ext_vector_type(4)));

#define MFMA16 __builtin_amdgcn_mfma_f32_16x16x32_bf16

__device__ __forceinline__ unsigned short f2b(float f) {
  return __builtin_bit_cast(unsigned short, (__bf16)f);
}

// ---------------------------------------------------------------------------
// Kernel 0: W (fp32) -> bf16, all three weight matrices
// ---------------------------------------------------------------------------
__global__ __launch_bounds__(256) void k_wconv(const float* __restrict__ Wa,
                                               const float* __restrict__ Wb,
                                               const float* __restrict__ Wm,
                                               unsigned short* __restrict__ W16) {
  const int m = blockIdx.y;
  const float* W = (m == 0) ? Wa : (m == 1) ? Wb : Wm;
  const int i = (blockIdx.x * 256 + threadIdx.x) * 8;
  float4 a = *reinterpret_cast<const float4*>(W + i);
  float4 b = *reinterpret_cast<const float4*>(W + i + 4);
  ushort4 lo, hi;
  lo.x = f2b(a.x); lo.y = f2b(a.y); lo.z = f2b(a.z); lo.w = f2b(a.w);
  hi.x = f2b(b.x); hi.y = f2b(b.y); hi.z = f2b(b.z); hi.w = f2b(b.w);
  unsigned short* dst = W16 + m * 65536 + i;
  *reinterpret_cast<ushort4*>(dst) = lo;
  *reinterpret_cast<ushort4*>(dst + 4) = hi;
}

// ---------------------------------------------------------------------------
// Kernel 1: XT[b][n][c] = (bf16) x[b][c][n]   (tiled transpose + cast)
// ---------------------------------------------------------------------------
__global__ __launch_bounds__(256) void k_transpose(const float* __restrict__ x,
                                                   unsigned short* __restrict__ xt) {
  __shared__ float tile[64][65];
  const int nt = blockIdx.x, ct = blockIdx.y, b = blockIdx.z;
  const int tid = threadIdx.x;
  const int j4 = (tid & 15) * 4, r0 = tid >> 4;
  const float* src = x + ((size_t)(b * 256 + ct * 64) * 4096) + nt * 64;
#pragma unroll
  for (int p = 0; p < 4; ++p) {
    int r = r0 + p * 16;
    float4 v = *reinterpret_cast<const float4*>(src + (size_t)r * 4096 + j4);
    tile[r][j4] = v.x; tile[r][j4 + 1] = v.y; tile[r][j4 + 2] = v.z; tile[r][j4 + 3] = v.w;
  }
  __syncthreads();
  unsigned short* dst = xt + ((size_t)(b * 4096 + nt * 64)) * 256 + ct * 64;
#pragma unroll
  for (int p = 0; p < 4; ++p) {
    int r = r0 + p * 16;
    ushort4 o;
    o.x = f2b(tile[j4][r]);
    o.y = f2b(tile[j4 + 1][r]);
    o.z = f2b(tile[j4 + 2][r]);
    o.w = f2b(tile[j4 + 3][r]);
    *reinterpret_cast<ushort4*>(dst + (size_t)r * 256 + j4) = o;
  }
}

// ---------------------------------------------------------------------------
// Kernel 2: projections (mode 0:Q=Wa, 1:K=Wb, 2:V=Wm+BN), W pre-cast to bf16
// ---------------------------------------------------------------------------
__global__ __launch_bounds__(256) void k_qkv(
    const unsigned short* __restrict__ xt, const unsigned short* __restrict__ W16,
    const float* __restrict__ ba, const float* __restrict__ bb,
    const float* __restrict__ bm, const float* __restrict__ gamma,
    const float* __restrict__ beta, const float* __restrict__ rmean,
    const float* __restrict__ rvar,
    unsigned short* __restrict__ Q, unsigned short* __restrict__ K,
    unsigned short* __restrict__ V) {
  const int nt = blockIdx.x, mode = blockIdx.y, b = blockIdx.z;
  const int tid = threadIdx.x, w = tid >> 6, l = tid & 63;
  const int li = l & 15, lk = l >> 4;
  const unsigned short* W = W16 + mode * 65536;
  const int row = nt * 64 + w * 16 + li;
  const unsigned short* arow = xt + ((size_t)b * 4096 + row) * 256;
  bf16x8 af[8];
#pragma unroll
  for (int kk = 0; kk < 8; ++kk)
    af[kk] = *reinterpret_cast<const bf16x8*>(arow + kk * 32 + lk * 8);
  f32x4 zero = {0.f, 0.f, 0.f, 0.f};
  f32x4 acc[16];
#pragma unroll
  for (int i = 0; i < 16; ++i) acc[i] = zero;
#pragma unroll
  for (int kk = 0; kk < 8; ++kk) {
#pragma unroll
    for (int of = 0; of < 16; ++of) {
      bf16x8 bfv = *reinterpret_cast<const bf16x8*>(W + (size_t)(of * 16 + li) * 256 + kk * 32 + lk * 8);
      acc[of] = MFMA16(af[kk], bfv, acc[of], 0, 0, 0);
    }
  }
  if (mode < 2) {
    const float* bias = (mode == 0) ? ba : bb;
    unsigned short* out = ((mode == 0) ? Q : K) + ((size_t)b * 4096 + nt * 64 + w * 16) * 256;
#pragma unroll
    for (int of = 0; of < 16; ++of) {
      int c = of * 16 + li;
      float bs = bias[c];
#pragma unroll
      for (int r = 0; r < 4; ++r)
        out[(size_t)(lk * 4 + r) * 256 + c] = f2b(acc[of][r] + bs);
    }
  } else {
    unsigned short* out = V + (size_t)b * 256 * 4096;
    const int n0 = nt * 64 + w * 16 + lk * 4;
#pragma unroll
    for (int of = 0; of < 16; ++of) {
      int c = of * 16 + li;
      float g = rsqrtf(rvar[c] + 1e-5f) * gamma[c];
      float sh = (bm[c] - rmean[c]) * g + beta[c];
      ushort4 o4;
      o4.x = f2b(acc[of][0] * g + sh);
      o4.y = f2b(acc[of][1] * g + sh);
      o4.z = f2b(acc[of][2] * g + sh);
      o4.w = f2b(acc[of][3] * g + sh);
      *reinterpret_cast<ushort4*>(out + (size_t)c * 4096 + n0) = o4;
    }
  }
}

// ---------------------------------------------------------------------------
// Kernel 3: flash attention, split-K. Grid 1024 = 64 qt x 4 splits x 4 b.
//   4 waves/block, 40 KiB LDS -> 4 blocks/CU, 16 waves/CU.
//   Writes unnormalized partial acc (bf16) + m,l per (split, q-row).
// ---------------------------------------------------------------------------
__global__ __launch_bounds__(256, 4) void k_attn(
    const unsigned short* __restrict__ Q, const unsigned short* __restrict__ K,
    const unsigned short* __restrict__ V, unsigned short* __restrict__ part,
    float* __restrict__ mpart, float* __restrict__ lpart) {
  constexpr int VP = 40;  // V row pad (80B rows: 16B-aligned, conflict-spread)
  __shared__ unsigned short K_lds[32 * 256];  // XOR-swizzled 16B chunks
  __shared__ unsigned short V_lds[256 * VP];
  __shared__ unsigned short P_lds[64 * 32];
  // XCD swizzle: nwg=1024 (%8==0, bijective). XCD x hosts (b,s) pairs {2x,2x+1}:
  // per-XCD K/V working set = 2 x (256KB+256KB) = 1MB -> L2-resident.
  const int bid = blockIdx.x;
  const int swz = (bid & 7) * 128 + (bid >> 3);
  const int qt = swz & 63;
  const int bs = swz >> 6;
  const int b = bs >> 2, s = bs & 3;
  const int tid = threadIdx.x, w = tid >> 6, l = tid & 63;
  const int li = l & 15, lk = l >> 4;
  const int q0 = qt * 64;
  const unsigned short* qp = Q + ((size_t)b * 4096 + q0 + w * 16 + li) * 256;
  bf16x8 qf[8];
#pragma unroll
  for (int kk = 0; kk < 8; ++kk)
    qf[kk] = *reinterpret_cast<const bf16x8*>(qp + kk * 32 + lk * 8);
  f32x4 zero = {0.f, 0.f, 0.f, 0.f};
  f32x4 acc[16];
#pragma unroll
  for (int i = 0; i < 16; ++i) acc[i] = zero;
  float mr[4] = {-1e30f, -1e30f, -1e30f, -1e30f};
  float lr[4] = {0.f, 0.f, 0.f, 0.f};

  for (int kt = 0; kt < 32; ++kt) {
    const int k0 = s * 1024 + kt * 32;
    // stage K tile [32 keys][256 c], 16B chunks XOR-swizzled by row
#pragma unroll
    for (int p = 0; p < 4; ++p) {
      int task = p * 256 + tid;
      int r = task >> 5, ch = task & 31;
      bf16x8 v = *reinterpret_cast<const bf16x8*>(K + ((size_t)b * 4096 + k0 + r) * 256 + ch * 8);
      *reinterpret_cast<bf16x8*>(&K_lds[r * 256 + ((ch ^ (r & 15)) << 3)]) = v;
    }
    // stage V tile [256 c][32 keys]
#pragma unroll
    for (int p = 0; p < 4; ++p) {
      int task = p * 256 + tid;
      int r = task >> 2, ch = task & 3;
      bf16x8 v = *reinterpret_cast<const bf16x8*>(V + ((size_t)b * 256 + r) * 4096 + k0 + ch * 8);
      *reinterpret_cast<bf16x8*>(&V_lds[r * VP + ch * 8]) = v;
    }
    __syncthreads();
    // S[16 n][32 m] = Q . K^T
    f32x4 sj[2] = {zero, zero};
#pragma unroll
    for (int kk = 0; kk < 8; ++kk) {
#pragma unroll
      for (int jf = 0; jf < 2; ++jf) {
        int row = jf * 16 + li;
        bf16x8 kf = *reinterpret_cast<const bf16x8*>(
            &K_lds[row * 256 + (((kk * 4 + lk) ^ li) << 3)]);
        sj[jf] = MFMA16(qf[kk], kf, sj[jf], 0, 0, 0);
      }
    }
    // online softmax (row r spans the 16 li-lanes of this lk-group)
    float sc[4];
#pragma unroll
    for (int r = 0; r < 4; ++r) {
      float pm = fmaxf(sj[0][r], sj[1][r]);
      pm = fmaxf(pm, __shfl_xor(pm, 1));
      pm = fmaxf(pm, __shfl_xor(pm, 2));
      pm = fmaxf(pm, __shfl_xor(pm, 4));
      pm = fmaxf(pm, __shfl_xor(pm, 8));
      float nm = fmaxf(mr[r], pm);
      sc[r] = __expf(mr[r] - nm);
      mr[r] = nm;
      float sum = 0.f;
#pragma unroll
      for (int jf = 0; jf < 2; ++jf) {
        float pv = __expf(sj[jf][r] - nm);
        sum += pv;
        P_lds[(w * 16 + lk * 4 + r) * 32 + jf * 16 + li] = f2b(pv);
      }
      sum += __shfl_xor(sum, 1);
      sum += __shfl_xor(sum, 2);
      sum += __shfl_xor(sum, 4);
      sum += __shfl_xor(sum, 8);
      lr[r] = lr[r] * sc[r] + sum;
    }
#pragma unroll
    for (int cf = 0; cf < 16; ++cf) {
#pragma unroll
      for (int r = 0; r < 4; ++r) acc[cf][r] *= sc[r];
    }
    __syncthreads();  // P visible; K_lds reads done before restage
    // O[16 n][256 c] += P . V^T   (single K=32 step)
    bf16x8 pf = *reinterpret_cast<const bf16x8*>(&P_lds[(w * 16 + li) * 32 + lk * 8]);
#pragma unroll
    for (int cf = 0; cf < 16; ++cf) {
      bf16x8 vf = *reinterpret_cast<const bf16x8*>(&V_lds[(cf * 16 + li) * VP + lk * 8]);
      acc[cf] = MFMA16(pf, vf, acc[cf], 0, 0, 0);
    }
    __syncthreads();  // protect K_lds/V_lds before next stage
  }
  // store unnormalized partial [s][b][q][c] bf16 + per-row m,l
  size_t pbase = (((size_t)(s * 4 + b)) * 4096 + q0 + w * 16) * 256;
#pragma unroll
  for (int cf = 0; cf < 16; ++cf) {
#pragma unroll
    for (int r = 0; r < 4; ++r)
      part[pbase + (size_t)(lk * 4 + r) * 256 + cf * 16 + li] = f2b(acc[cf][r]);
  }
  if (li == 0) {
#pragma unroll
    for (int r = 0; r < 4; ++r) {
      int idx = (s * 4 + b) * 4096 + q0 + w * 16 + lk * 4 + r;
      mpart[idx] = mr[r];
      lpart[idx] = lr[r];
    }
  }
}

// ---------------------------------------------------------------------------
// Kernel 4: combine splits + residual epilogue (transpose back to [b][c][n])
// ---------------------------------------------------------------------------
__global__ __launch_bounds__(256) void k_comb(
    const unsigned short* __restrict__ part, const float* __restrict__ mpart,
    const float* __restrict__ lpart, const float* __restrict__ feat,
    const float* __restrict__ alpha, float* __restrict__ out) {
  __shared__ float wgt[4][64];
  __shared__ float tile[64][261];
  const int nt = blockIdx.x, b = blockIdx.y;
  const int n0 = nt * 64;
  const int tid = threadIdx.x;
  if (tid < 64) {
    int q = n0 + tid;
    float m[4], lv[4];
#pragma unroll
    for (int s = 0; s < 4; ++s) {
      m[s] = mpart[(s * 4 + b) * 4096 + q];
      lv[s] = lpart[(s * 4 + b) * 4096 + q];
    }
    float M = fmaxf(fmaxf(m[0], m[1]), fmaxf(m[2], m[3]));
    float e[4], L = 0.f;
#pragma unroll
    for (int s = 0; s < 4; ++s) { e[s] = __expf(m[s] - M); L += e[s] * lv[s]; }
    float inv = 1.0f / L;
#pragma unroll
    for (int s = 0; s < 4; ++s) wgt[s][tid] = e[s] * inv;
  }
  __syncthreads();
  const int row = tid >> 2;
  const int c0 = (tid & 3) * 64;
  float acc[64];
#pragma unroll
  for (int k = 0; k < 64; ++k) acc[k] = 0.f;
  for (int s = 0; s < 4; ++s) {
    float ww = wgt[s][row];
    const unsigned short* p = part + (((size_t)(s * 4 + b)) * 4096 + n0 + row) * 256 + c0;
#pragma unroll
    for (int ch = 0; ch < 8; ++ch) {
      bf16x8 v = *reinterpret_cast<const bf16x8*>(p + ch * 8);
#pragma unroll
      for (int j = 0; j < 8; ++j) acc[ch * 8 + j] += ww * (float)v[j];
    }
  }
#pragma unroll
  for (int k = 0; k < 64; ++k) tile[row][c0 + k] = acc[k];
  __syncthreads();
  const float av = alpha[0];
  const int j = tid & 15, cb = tid >> 4;
#pragma unroll
  for (int p = 0; p < 16; ++p) {
    int c = cb * 16 + p;
    size_t gbase = ((size_t)(b * 256 + c)) * 4096 + n0 + j * 4;
    float4 f4 = *reinterpret_cast<const float4*>(feat + gbase);
    float4 o;
    o.x = f4.x + av * tile[j * 4 + 0][c];
    o.y = f4.y + av * tile[j * 4 + 1][c];
    o.z = f4.z + av * tile[j * 4 + 2][c];
    o.w = f4.w + av * tile[j * 4 + 3][c];
    *reinterpret_cast<float4*>(out + gbase) = o;
  }
}

extern "C" void kernel_launch(void* const* d_in, const int* in_sizes, int n_in,
                              void* d_out, int out_size, void* d_ws, size_t ws_size,
                              hipStream_t stream) {
  const float* feat  = (const float*)d_in[0];
  const float* Wa    = (const float*)d_in[1];
  const float* ba    = (const float*)d_in[2];
  const float* Wb    = (const float*)d_in[3];
  const float* bb    = (const float*)d_in[4];
  const float* Wm    = (const float*)d_in[5];
  const float* bm    = (const float*)d_in[6];
  const float* gamma = (const float*)d_in[7];
  const float* beta  = (const float*)d_in[8];
  const float* rmean = (const float*)d_in[9];
  const float* rvar  = (const float*)d_in[10];
  const float* alpha = (const float*)d_in[11];
  float* out = (float*)d_out;
  char* ws = (char*)d_ws;
  // layout (part aliases XT: XT dead after k_qkv, part written by k_attn)
  unsigned short* Qb   = (unsigned short*)(ws);                    // [0,8M)
  unsigned short* Kb   = (unsigned short*)(ws + ((size_t)8 << 20));   // [8M,16M)
  unsigned short* Vb   = (unsigned short*)(ws + ((size_t)16 << 20));  // [16M,24M)
  unsigned short* XT   = (unsigned short*)(ws + ((size_t)24 << 20));  // [24M,32M)
  unsigned short* part = (unsigned short*)(ws + ((size_t)24 << 20));  // [24M,56M)
  unsigned short* W16  = (unsigned short*)(ws + ((size_t)56 << 20));  // 384K
  float* mpart = (float*)(ws + ((size_t)56 << 20) + 393216);          // 256K
  float* lpart = (float*)(ws + ((size_t)56 << 20) + 393216 + 262144); // 256K

  k_wconv<<<dim3(32, 3), 256, 0, stream>>>(Wa, Wb, Wm, W16);
  k_transpose<<<dim3(64, 4, 4), 256, 0, stream>>>(feat, XT);
  k_qkv<<<dim3(64, 3, 4), 256, 0, stream>>>(XT, W16, ba, bb, bm, gamma, beta,
                                            rmean, rvar, Qb, Kb, Vb);
  k_attn<<<dim3(1024), dim3(256), 0, stream>>>(Qb, Kb, Vb, part, mpart, lpart);
  k_comb<<<dim3(64, 4), 256, 0, stream>>>(part, mpart, lpart, feat, alpha, out);
}

// Round 3
// 199.841 us; speedup vs baseline: 3.0161x; 1.6721x over previous
//
#include <hip/hip_runtime.h>
#include <hip/hip_bf16.h>

typedef __bf16 bf16x8 __attribute__((ext_vector_type(8)));
typedef float f32x4 __attribute__((ext_vector_type(4)));
typedef float f32x16 __attribute__((ext_vector_type(16)));

#define MFMA16 __builtin_amdgcn_mfma_f32_16x16x32_bf16
#define MFMA32 __builtin_amdgcn_mfma_f32_32x32x16_bf16

__device__ __forceinline__ unsigned short f2b(float f) {
  return __builtin_bit_cast(unsigned short, (__bf16)f);
}

__device__ __forceinline__ void gload_lds16(const void* g, void* l) {
  __builtin_amdgcn_global_load_lds(
      (const __attribute__((address_space(1))) unsigned int*)g,
      (__attribute__((address_space(3))) unsigned int*)l, 16, 0, 0);
}

// ---------------------------------------------------------------------------
// Kernel 0: W (fp32) -> bf16
// ---------------------------------------------------------------------------
__global__ __launch_bounds__(256) void k_wconv(const float* __restrict__ Wa,
                                               const float* __restrict__ Wb,
                                               const float* __restrict__ Wm,
                                               unsigned short* __restrict__ W16) {
  const int m = blockIdx.y;
  const float* W = (m == 0) ? Wa : (m == 1) ? Wb : Wm;
  const int i = (blockIdx.x * 256 + threadIdx.x) * 8;
  float4 a = *reinterpret_cast<const float4*>(W + i);
  float4 b = *reinterpret_cast<const float4*>(W + i + 4);
  ushort4 lo, hi;
  lo.x = f2b(a.x); lo.y = f2b(a.y); lo.z = f2b(a.z); lo.w = f2b(a.w);
  hi.x = f2b(b.x); hi.y = f2b(b.y); hi.z = f2b(b.z); hi.w = f2b(b.w);
  unsigned short* dst = W16 + m * 65536 + i;
  *reinterpret_cast<ushort4*>(dst) = lo;
  *reinterpret_cast<ushort4*>(dst + 4) = hi;
}

// ---------------------------------------------------------------------------
// Kernel 1: XT[b][n][c] = (bf16) x[b][c][n]
// ---------------------------------------------------------------------------
__global__ __launch_bounds__(256) void k_transpose(const float* __restrict__ x,
                                                   unsigned short* __restrict__ xt) {
  __shared__ float tile[64][65];
  const int nt = blockIdx.x, ct = blockIdx.y, b = blockIdx.z;
  const int tid = threadIdx.x;
  const int j4 = (tid & 15) * 4, r0 = tid >> 4;
  const float* src = x + ((size_t)(b * 256 + ct * 64) * 4096) + nt * 64;
#pragma unroll
  for (int p = 0; p < 4; ++p) {
    int r = r0 + p * 16;
    float4 v = *reinterpret_cast<const float4*>(src + (size_t)r * 4096 + j4);
    tile[r][j4] = v.x; tile[r][j4 + 1] = v.y; tile[r][j4 + 2] = v.z; tile[r][j4 + 3] = v.w;
  }
  __syncthreads();
  unsigned short* dst = xt + ((size_t)(b * 4096 + nt * 64)) * 256 + ct * 64;
#pragma unroll
  for (int p = 0; p < 4; ++p) {
    int r = r0 + p * 16;
    ushort4 o;
    o.x = f2b(tile[j4][r]);
    o.y = f2b(tile[j4 + 1][r]);
    o.z = f2b(tile[j4 + 2][r]);
    o.w = f2b(tile[j4 + 3][r]);
    *reinterpret_cast<ushort4*>(dst + (size_t)r * 256 + j4) = o;
  }
}

// ---------------------------------------------------------------------------
// Kernel 2: projections (mode 0:Q=Wa, 1:K=Wb, 2:V=Wm+BN)
// ---------------------------------------------------------------------------
__global__ __launch_bounds__(256) void k_qkv(
    const unsigned short* __restrict__ xt, const unsigned short* __restrict__ W16,
    const float* __restrict__ ba, const float* __restrict__ bb,
    const float* __restrict__ bm, const float* __restrict__ gamma,
    const float* __restrict__ beta, const float* __restrict__ rmean,
    const float* __restrict__ rvar,
    unsigned short* __restrict__ Q, unsigned short* __restrict__ K,
    unsigned short* __restrict__ V) {
  const int nt = blockIdx.x, mode = blockIdx.y, b = blockIdx.z;
  const int tid = threadIdx.x, w = tid >> 6, l = tid & 63;
  const int li = l & 15, lk = l >> 4;
  const unsigned short* W = W16 + mode * 65536;
  const int row = nt * 64 + w * 16 + li;
  const unsigned short* arow = xt + ((size_t)b * 4096 + row) * 256;
  bf16x8 af[8];
#pragma unroll
  for (int kk = 0; kk < 8; ++kk)
    af[kk] = *reinterpret_cast<const bf16x8*>(arow + kk * 32 + lk * 8);
  f32x4 zero = {0.f, 0.f, 0.f, 0.f};
  f32x4 acc[16];
#pragma unroll
  for (int i = 0; i < 16; ++i) acc[i] = zero;
#pragma unroll
  for (int kk = 0; kk < 8; ++kk) {
#pragma unroll
    for (int of = 0; of < 16; ++of) {
      bf16x8 bfv = *reinterpret_cast<const bf16x8*>(W + (size_t)(of * 16 + li) * 256 + kk * 32 + lk * 8);
      acc[of] = MFMA16(af[kk], bfv, acc[of], 0, 0, 0);
    }
  }
  if (mode < 2) {
    const float* bias = (mode == 0) ? ba : bb;
    unsigned short* out = ((mode == 0) ? Q : K) + ((size_t)b * 4096 + nt * 64 + w * 16) * 256;
#pragma unroll
    for (int of = 0; of < 16; ++of) {
      int c = of * 16 + li;
      float bs = bias[c];
#pragma unroll
      for (int r = 0; r < 4; ++r)
        out[(size_t)(lk * 4 + r) * 256 + c] = f2b(acc[of][r] + bs);
    }
  } else {
    unsigned short* out = V + (size_t)b * 256 * 4096;
    const int n0 = nt * 64 + w * 16 + lk * 4;
#pragma unroll
    for (int of = 0; of < 16; ++of) {
      int c = of * 16 + li;
      float g = rsqrtf(rvar[c] + 1e-5f) * gamma[c];
      float sh = (bm[c] - rmean[c]) * g + beta[c];
      ushort4 o4;
      o4.x = f2b(acc[of][0] * g + sh);
      o4.y = f2b(acc[of][1] * g + sh);
      o4.z = f2b(acc[of][2] * g + sh);
      o4.w = f2b(acc[of][3] * g + sh);
      *reinterpret_cast<ushort4*>(out + (size_t)c * 4096 + n0) = o4;
    }
  }
}

// ---------------------------------------------------------------------------
// Kernel 3: flash attention, split-K, swapped-QK^T 32x32x16 MFMA.
//   Grid 512 = 32 qt x 4 s x 4 b. 4 waves x 32 queries = 128 q/block.
//   KVBLK=32, K/V double-buffered via global_load_lds (pre-swizzled source),
//   softmax fully in-lane, P via tiny per-wave LDS, 2 blocks/CU.
// ---------------------------------------------------------------------------
__global__ __launch_bounds__(256, 2) void k_attn(
    const unsigned short* __restrict__ Q, const unsigned short* __restrict__ K,
    const unsigned short* __restrict__ V, unsigned short* __restrict__ part,
    float* __restrict__ mpart, float* __restrict__ lpart) {
  __shared__ unsigned short K_lds[2][32 * 256];  // [key][c], chunk ^= key&7
  __shared__ unsigned short V_lds[2][256 * 32];  // [c][key], chunk ^= c&3
  __shared__ unsigned short P_lds[4][32 * 36];   // per-wave [q][key], pitch 36
  const int bid = blockIdx.x;
  const int swz = (bid & 7) * 64 + (bid >> 3);  // XCD-contiguous, bijective
  const int qt = swz & 31;
  const int bs = swz >> 5;
  const int b = bs >> 2, s = bs & 3;
  const int tid = threadIdx.x, w = tid >> 6, l = tid & 63;
  const int q = l & 31, hi = l >> 5;
  const int rowq = qt * 128 + w * 32 + q;
  // Q fragments (B-operand): lane holds Q[rowq][kk*16 + hi*8 .. +8]
  bf16x8 qf[16];
  const unsigned short* qp = Q + ((size_t)b * 4096 + rowq) * 256 + hi * 8;
#pragma unroll
  for (int kk = 0; kk < 16; ++kk)
    qf[kk] = *reinterpret_cast<const bf16x8*>(qp + kk * 16);
  f32x16 acc[8];
#pragma unroll
  for (int i = 0; i < 8; ++i)
#pragma unroll
    for (int r = 0; r < 16; ++r) acc[i][r] = 0.f;
  float mr = -3e38f, lr = 0.f;

  auto stageK = [&](int buf, int k0) {
#pragma unroll
    for (int i = 0; i < 4; ++i) {
      int row = w * 8 + i * 2 + hi;
      const unsigned short* src =
          K + ((size_t)b * 4096 + k0 + row) * 256 + ((q ^ (row & 7)) * 8);
      gload_lds16(src, &K_lds[buf][(w * 8 + i * 2) * 256]);
    }
  };
  auto stageV = [&](int buf, int k0) {
#pragma unroll
    for (int i = 0; i < 4; ++i) {
      int c = w * 64 + i * 16 + (l >> 2);
      int ch = l & 3;
      const unsigned short* src =
          V + ((size_t)b * 256 + c) * 4096 + k0 + ((ch ^ (c & 3)) * 8);
      gload_lds16(src, &V_lds[buf][(w * 64 + i * 16) * 32]);
    }
  };

  const int kbase = s * 1024;
  stageK(0, kbase);
  stageV(0, kbase);
  asm volatile("s_waitcnt vmcnt(0)" ::: "memory");
  __syncthreads();
  int cur = 0;
  for (int t = 0; t < 32; ++t) {
    if (t < 31) { stageK(cur ^ 1, kbase + (t + 1) * 32); stageV(cur ^ 1, kbase + (t + 1) * 32); }
    // ---- QK^T (swapped): S[key][q] ----
    f32x16 S;
#pragma unroll
    for (int r = 0; r < 16; ++r) S[r] = 0.f;
    __builtin_amdgcn_s_setprio(1);
#pragma unroll
    for (int kk = 0; kk < 16; ++kk) {
      int chunk = (kk * 2 + hi) ^ (q & 7);
      bf16x8 kf = *reinterpret_cast<const bf16x8*>(&K_lds[cur][q * 256 + chunk * 8]);
      S = MFMA32(kf, qf[kk], S, 0, 0, 0);
    }
    __builtin_amdgcn_s_setprio(0);
    // ---- online softmax, fully in-lane (16 keys here, other 16 in lane^32) ----
    float pmax = S[0];
#pragma unroll
    for (int r = 1; r < 16; ++r) pmax = fmaxf(pmax, S[r]);
    pmax = fmaxf(pmax, __shfl_xor(pmax, 32));
    if (!__all(pmax - mr <= 8.0f)) {  // defer-max (THR=8)
      float nm = fmaxf(mr, pmax);
      float sc = __expf(mr - nm);
      mr = nm;
      lr *= sc;
#pragma unroll
      for (int cb = 0; cb < 8; ++cb)
#pragma unroll
        for (int r = 0; r < 16; ++r) acc[cb][r] *= sc;
    }
    float p[16];
    float sum = 0.f;
#pragma unroll
    for (int r = 0; r < 16; ++r) { p[r] = __expf(S[r] - mr); sum += p[r]; }
    sum += __shfl_xor(sum, 32);
    lr += sum;
    // ---- P -> per-wave LDS (rows q, keys crow(r,hi)=g*8+hi*4+(r&3)) ----
#pragma unroll
    for (int g = 0; g < 4; ++g) {
      ushort4 pk;
      pk.x = f2b(p[g * 4 + 0]); pk.y = f2b(p[g * 4 + 1]);
      pk.z = f2b(p[g * 4 + 2]); pk.w = f2b(p[g * 4 + 3]);
      *reinterpret_cast<ushort4*>(&P_lds[w][q * 36 + g * 8 + hi * 4]) = pk;
    }
    // ---- PV: O[q][c] += P[q][k] V[k][c] ----
    bf16x8 pa[2];
#pragma unroll
    for (int ks = 0; ks < 2; ++ks)
      pa[ks] = *reinterpret_cast<const bf16x8*>(&P_lds[w][q * 36 + ks * 16 + hi * 8]);
    __builtin_amdgcn_s_setprio(1);
#pragma unroll
    for (int ks = 0; ks < 2; ++ks)
#pragma unroll
      for (int cb = 0; cb < 8; ++cb) {
        int c = cb * 32 + q;
        int chunk = (ks * 2 + hi) ^ (q & 3);
        bf16x8 vb = *reinterpret_cast<const bf16x8*>(&V_lds[cur][c * 32 + chunk * 8]);
        acc[cb] = MFMA32(pa[ks], vb, acc[cb], 0, 0, 0);
      }
    __builtin_amdgcn_s_setprio(0);
    asm volatile("s_waitcnt vmcnt(0)" ::: "memory");
    __syncthreads();
    cur ^= 1;
  }
  // ---- store partial: part[sb][q][c], c = cb*32 + g*8 + hi*4 + (r&3) ----
  const int sb = s * 4 + b;
  size_t pbase = ((size_t)sb * 4096 + rowq) * 256;
#pragma unroll
  for (int cb = 0; cb < 8; ++cb)
#pragma unroll
    for (int g = 0; g < 4; ++g) {
      ushort4 o;
      o.x = f2b(acc[cb][g * 4 + 0]); o.y = f2b(acc[cb][g * 4 + 1]);
      o.z = f2b(acc[cb][g * 4 + 2]); o.w = f2b(acc[cb][g * 4 + 3]);
      *reinterpret_cast<ushort4*>(&part[pbase + cb * 32 + g * 8 + hi * 4]) = o;
    }
  if (hi == 0) {
    mpart[sb * 4096 + rowq] = mr;
    lpart[sb * 4096 + rowq] = lr;
  }
}

// ---------------------------------------------------------------------------
// Kernel 4: combine splits + residual epilogue
// ---------------------------------------------------------------------------
__global__ __launch_bounds__(256) void k_comb(
    const unsigned short* __restrict__ part, const float* __restrict__ mpart,
    const float* __restrict__ lpart, const float* __restrict__ feat,
    const float* __restrict__ alpha, float* __restrict__ out) {
  __shared__ float wgt[4][64];
  __shared__ float tile[64][261];
  const int nt = blockIdx.x, b = blockIdx.y;
  const int n0 = nt * 64;
  const int tid = threadIdx.x;
  if (tid < 64) {
    int qn = n0 + tid;
    float m[4], lv[4];
#pragma unroll
    for (int s = 0; s < 4; ++s) {
      m[s] = mpart[(s * 4 + b) * 4096 + qn];
      lv[s] = lpart[(s * 4 + b) * 4096 + qn];
    }
    float M = fmaxf(fmaxf(m[0], m[1]), fmaxf(m[2], m[3]));
    float e[4], L = 0.f;
#pragma unroll
    for (int s = 0; s < 4; ++s) { e[s] = __expf(m[s] - M); L += e[s] * lv[s]; }
    float inv = 1.0f / L;
#pragma unroll
    for (int s = 0; s < 4; ++s) wgt[s][tid] = e[s] * inv;
  }
  __syncthreads();
  const int row = tid >> 2;
  const int c0 = (tid & 3) * 64;
  float acc[64];
#pragma unroll
  for (int k = 0; k < 64; ++k) acc[k] = 0.f;
  for (int s = 0; s < 4; ++s) {
    float ww = wgt[s][row];
    const unsigned short* p = part + (((size_t)(s * 4 + b)) * 4096 + n0 + row) * 256 + c0;
#pragma unroll
    for (int ch = 0; ch < 8; ++ch) {
      bf16x8 v = *reinterpret_cast<const bf16x8*>(p + ch * 8);
#pragma unroll
      for (int j = 0; j < 8; ++j) acc[ch * 8 + j] += ww * (float)v[j];
    }
  }
#pragma unroll
  for (int k = 0; k < 64; ++k) tile[row][c0 + k] = acc[k];
  __syncthreads();
  const float av = alpha[0];
  const int j = tid & 15, cb = tid >> 4;
#pragma unroll
  for (int p = 0; p < 16; ++p) {
    int c = cb * 16 + p;
    size_t gbase = ((size_t)(b * 256 + c)) * 4096 + n0 + j * 4;
    float4 f4 = *reinterpret_cast<const float4*>(feat + gbase);
    float4 o;
    o.x = f4.x + av * tile[j * 4 + 0][c];
    o.y = f4.y + av * tile[j * 4 + 1][c];
    o.z = f4.z + av * tile[j * 4 + 2][c];
    o.w = f4.w + av * tile[j * 4 + 3][c];
    *reinterpret_cast<float4*>(out + gbase) = o;
  }
}

extern "C" void kernel_launch(void* const* d_in, const int* in_sizes, int n_in,
                              void* d_out, int out_size, void* d_ws, size_t ws_size,
                              hipStream_t stream) {
  const float* feat  = (const float*)d_in[0];
  const float* Wa    = (const float*)d_in[1];
  const float* ba    = (const float*)d_in[2];
  const float* Wb    = (const float*)d_in[3];
  const float* bb    = (const float*)d_in[4];
  const float* Wm    = (const float*)d_in[5];
  const float* bm    = (const float*)d_in[6];
  const float* gamma = (const float*)d_in[7];
  const float* beta  = (const float*)d_in[8];
  const float* rmean = (const float*)d_in[9];
  const float* rvar  = (const float*)d_in[10];
  const float* alpha = (const float*)d_in[11];
  float* out = (float*)d_out;
  char* ws = (char*)d_ws;
  unsigned short* Qb   = (unsigned short*)(ws);                       // [0,8M)
  unsigned short* Kb   = (unsigned short*)(ws + ((size_t)8 << 20));   // [8M,16M)
  unsigned short* Vb   = (unsigned short*)(ws + ((size_t)16 << 20));  // [16M,24M)
  unsigned short* XT   = (unsigned short*)(ws + ((size_t)24 << 20));  // [24M,32M)
  unsigned short* part = (unsigned short*)(ws + ((size_t)24 << 20));  // [24M,56M)
  unsigned short* W16  = (unsigned short*)(ws + ((size_t)56 << 20));  // 384K
  float* mpart = (float*)(ws + ((size_t)56 << 20) + 393216);
  float* lpart = (float*)(ws + ((size_t)56 << 20) + 393216 + 262144);

  k_wconv<<<dim3(32, 3), 256, 0, stream>>>(Wa, Wb, Wm, W16);
  k_transpose<<<dim3(64, 4, 4), 256, 0, stream>>>(feat, XT);
  k_qkv<<<dim3(64, 3, 4), 256, 0, stream>>>(XT, W16, ba, bb, bm, gamma, beta,
                                            rmean, rvar, Qb, Kb, Vb);
  k_attn<<<dim3(512), dim3(256), 0, stream>>>(Qb, Kb, Vb, part, mpart, lpart);
  k_comb<<<dim3(64, 4), 256, 0, stream>>>(part, mpart, lpart, feat, alpha, out);
}

// Round 4
// 176.819 us; speedup vs baseline: 3.4088x; 1.1302x over previous
//
#include <hip/hip_runtime.h>
#include <hip/hip_bf16.h>

typedef __bf16 bf16x8 __attribute__((ext_vector_type(8)));
typedef float f32x4 __attribute__((ext_vector_type(4)));
typedef float f32x16 __attribute__((ext_vector_type(16)));

#define MFMA16 __builtin_amdgcn_mfma_f32_16x16x32_bf16
#define MFMA32 __builtin_amdgcn_mfma_f32_32x32x16_bf16

__device__ __forceinline__ unsigned short f2b(float f) {
  return __builtin_bit_cast(unsigned short, (__bf16)f);
}

__device__ __forceinline__ void gload_lds16(const void* g, void* l) {
  __builtin_amdgcn_global_load_lds(
      (const __attribute__((address_space(1))) unsigned int*)g,
      (__attribute__((address_space(3))) unsigned int*)l, 16, 0, 0);
}

// ---------------------------------------------------------------------------
// Kernel 0: W (fp32) -> bf16
// ---------------------------------------------------------------------------
__global__ __launch_bounds__(256) void k_wconv(const float* __restrict__ Wa,
                                               const float* __restrict__ Wb,
                                               const float* __restrict__ Wm,
                                               unsigned short* __restrict__ W16) {
  const int m = blockIdx.y;
  const float* W = (m == 0) ? Wa : (m == 1) ? Wb : Wm;
  const int i = (blockIdx.x * 256 + threadIdx.x) * 8;
  float4 a = *reinterpret_cast<const float4*>(W + i);
  float4 b = *reinterpret_cast<const float4*>(W + i + 4);
  ushort4 lo, hi;
  lo.x = f2b(a.x); lo.y = f2b(a.y); lo.z = f2b(a.z); lo.w = f2b(a.w);
  hi.x = f2b(b.x); hi.y = f2b(b.y); hi.z = f2b(b.z); hi.w = f2b(b.w);
  unsigned short* dst = W16 + m * 65536 + i;
  *reinterpret_cast<ushort4*>(dst) = lo;
  *reinterpret_cast<ushort4*>(dst + 4) = hi;
}

// ---------------------------------------------------------------------------
// Kernel 1: XT[b][n][c] = (bf16) x[b][c][n]
// ---------------------------------------------------------------------------
__global__ __launch_bounds__(256) void k_transpose(const float* __restrict__ x,
                                                   unsigned short* __restrict__ xt) {
  __shared__ float tile[64][65];
  const int nt = blockIdx.x, ct = blockIdx.y, b = blockIdx.z;
  const int tid = threadIdx.x;
  const int j4 = (tid & 15) * 4, r0 = tid >> 4;
  const float* src = x + ((size_t)(b * 256 + ct * 64) * 4096) + nt * 64;
#pragma unroll
  for (int p = 0; p < 4; ++p) {
    int r = r0 + p * 16;
    float4 v = *reinterpret_cast<const float4*>(src + (size_t)r * 4096 + j4);
    tile[r][j4] = v.x; tile[r][j4 + 1] = v.y; tile[r][j4 + 2] = v.z; tile[r][j4 + 3] = v.w;
  }
  __syncthreads();
  unsigned short* dst = xt + ((size_t)(b * 4096 + nt * 64)) * 256 + ct * 64;
#pragma unroll
  for (int p = 0; p < 4; ++p) {
    int r = r0 + p * 16;
    ushort4 o;
    o.x = f2b(tile[j4][r]);
    o.y = f2b(tile[j4 + 1][r]);
    o.z = f2b(tile[j4 + 2][r]);
    o.w = f2b(tile[j4 + 3][r]);
    *reinterpret_cast<ushort4*>(dst + (size_t)r * 256 + j4) = o;
  }
}

// ---------------------------------------------------------------------------
// Kernel 2: projections (mode 0:Q=Wa, 1:K=Wb, 2:V=Wm+BN).
//   32 rows/wave (2 row-sets): each W-fragment load feeds 2 MFMAs -> half the
//   W L2 traffic of round 3. Block = 128 rows. Grid (32, 3, 4).
// ---------------------------------------------------------------------------
__global__ __launch_bounds__(256) void k_qkv(
    const unsigned short* __restrict__ xt, const unsigned short* __restrict__ W16,
    const float* __restrict__ ba, const float* __restrict__ bb,
    const float* __restrict__ bm, const float* __restrict__ gamma,
    const float* __restrict__ beta, const float* __restrict__ rmean,
    const float* __restrict__ rvar,
    unsigned short* __restrict__ Q, unsigned short* __restrict__ K,
    unsigned short* __restrict__ V) {
  const int nt = blockIdx.x, mode = blockIdx.y, b = blockIdx.z;
  const int tid = threadIdx.x, w = tid >> 6, l = tid & 63;
  const int li = l & 15, lk = l >> 4;
  const unsigned short* W = W16 + mode * 65536;
  bf16x8 af[2][8];
#pragma unroll
  for (int rs = 0; rs < 2; ++rs) {
    const int row = nt * 128 + w * 32 + rs * 16 + li;
    const unsigned short* arow = xt + ((size_t)b * 4096 + row) * 256;
#pragma unroll
    for (int kk = 0; kk < 8; ++kk)
      af[rs][kk] = *reinterpret_cast<const bf16x8*>(arow + kk * 32 + lk * 8);
  }
  f32x4 zero = {0.f, 0.f, 0.f, 0.f};
  f32x4 acc[2][16];
#pragma unroll
  for (int rs = 0; rs < 2; ++rs)
#pragma unroll
    for (int i = 0; i < 16; ++i) acc[rs][i] = zero;
#pragma unroll
  for (int kk = 0; kk < 8; ++kk) {
#pragma unroll
    for (int of = 0; of < 16; ++of) {
      bf16x8 bfv = *reinterpret_cast<const bf16x8*>(W + (size_t)(of * 16 + li) * 256 + kk * 32 + lk * 8);
      acc[0][of] = MFMA16(af[0][kk], bfv, acc[0][of], 0, 0, 0);
      acc[1][of] = MFMA16(af[1][kk], bfv, acc[1][of], 0, 0, 0);
    }
  }
  if (mode < 2) {
    const float* bias = (mode == 0) ? ba : bb;
#pragma unroll
    for (int rs = 0; rs < 2; ++rs) {
      unsigned short* out = ((mode == 0) ? Q : K) +
          ((size_t)b * 4096 + nt * 128 + w * 32 + rs * 16) * 256;
#pragma unroll
      for (int of = 0; of < 16; ++of) {
        int c = of * 16 + li;
        float bs = bias[c];
#pragma unroll
        for (int r = 0; r < 4; ++r)
          out[(size_t)(lk * 4 + r) * 256 + c] = f2b(acc[rs][of][r] + bs);
      }
    }
  } else {
    unsigned short* out = V + (size_t)b * 256 * 4096;
#pragma unroll
    for (int of = 0; of < 16; ++of) {
      int c = of * 16 + li;
      float g = rsqrtf(rvar[c] + 1e-5f) * gamma[c];
      float sh = (bm[c] - rmean[c]) * g + beta[c];
#pragma unroll
      for (int rs = 0; rs < 2; ++rs) {
        const int n0 = nt * 128 + w * 32 + rs * 16 + lk * 4;
        ushort4 o4;
        o4.x = f2b(acc[rs][of][0] * g + sh);
        o4.y = f2b(acc[rs][of][1] * g + sh);
        o4.z = f2b(acc[rs][of][2] * g + sh);
        o4.w = f2b(acc[rs][of][3] * g + sh);
        *reinterpret_cast<ushort4*>(out + (size_t)c * 4096 + n0) = o4;
      }
    }
  }
}

// ---------------------------------------------------------------------------
// Kernel 3: flash attention, split-K, swapped-QK^T 32x32x16 MFMA.
//   V LDS position swizzle uses (c>>1)&3 so each octet of lanes hits 8
//   distinct bank starts (was (c&3): aliased with row parity -> 2-way).
// ---------------------------------------------------------------------------
__global__ __launch_bounds__(256, 2) void k_attn(
    const unsigned short* __restrict__ Q, const unsigned short* __restrict__ K,
    const unsigned short* __restrict__ V, unsigned short* __restrict__ part,
    float* __restrict__ mpart, float* __restrict__ lpart) {
  __shared__ unsigned short K_lds[2][32 * 256];  // [key][c], chunk ^= key&7
  __shared__ unsigned short V_lds[2][256 * 32];  // [c][key], chunk ^= (c>>1)&3
  __shared__ unsigned short P_lds[4][32 * 36];   // per-wave [q][key], pitch 36
  const int bid = blockIdx.x;
  const int swz = (bid & 7) * 64 + (bid >> 3);  // XCD-contiguous, bijective
  const int qt = swz & 31;
  const int bs = swz >> 5;
  const int b = bs >> 2, s = bs & 3;
  const int tid = threadIdx.x, w = tid >> 6, l = tid & 63;
  const int q = l & 31, hi = l >> 5;
  const int rowq = qt * 128 + w * 32 + q;
  bf16x8 qf[16];
  const unsigned short* qp = Q + ((size_t)b * 4096 + rowq) * 256 + hi * 8;
#pragma unroll
  for (int kk = 0; kk < 16; ++kk)
    qf[kk] = *reinterpret_cast<const bf16x8*>(qp + kk * 16);
  f32x16 acc[8];
#pragma unroll
  for (int i = 0; i < 8; ++i)
#pragma unroll
    for (int r = 0; r < 16; ++r) acc[i][r] = 0.f;
  float mr = -3e38f, lr = 0.f;

  auto stageK = [&](int buf, int k0) {
#pragma unroll
    for (int i = 0; i < 4; ++i) {
      int row = w * 8 + i * 2 + hi;
      const unsigned short* src =
          K + ((size_t)b * 4096 + k0 + row) * 256 + ((q ^ (row & 7)) * 8);
      gload_lds16(src, &K_lds[buf][(w * 8 + i * 2) * 256]);
    }
  };
  auto stageV = [&](int buf, int k0) {
#pragma unroll
    for (int i = 0; i < 4; ++i) {
      int c = w * 64 + i * 16 + (l >> 2);
      int ch = (l & 3) ^ ((l >> 3) & 3);
      const unsigned short* src =
          V + ((size_t)b * 256 + c) * 4096 + k0 + ch * 8;
      gload_lds16(src, &V_lds[buf][(w * 64 + i * 16) * 32]);
    }
  };

  const int kbase = s * 1024;
  stageK(0, kbase);
  stageV(0, kbase);
  asm volatile("s_waitcnt vmcnt(0)" ::: "memory");
  __syncthreads();
  int cur = 0;
  for (int t = 0; t < 32; ++t) {
    if (t < 31) { stageK(cur ^ 1, kbase + (t + 1) * 32); stageV(cur ^ 1, kbase + (t + 1) * 32); }
    // ---- QK^T (swapped): S[key][q] ----
    f32x16 S;
#pragma unroll
    for (int r = 0; r < 16; ++r) S[r] = 0.f;
    __builtin_amdgcn_s_setprio(1);
#pragma unroll
    for (int kk = 0; kk < 16; ++kk) {
      int chunk = (kk * 2 + hi) ^ (q & 7);
      bf16x8 kf = *reinterpret_cast<const bf16x8*>(&K_lds[cur][q * 256 + chunk * 8]);
      S = MFMA32(kf, qf[kk], S, 0, 0, 0);
    }
    __builtin_amdgcn_s_setprio(0);
    // ---- online softmax, fully in-lane ----
    float pmax = S[0];
#pragma unroll
    for (int r = 1; r < 16; ++r) pmax = fmaxf(pmax, S[r]);
    pmax = fmaxf(pmax, __shfl_xor(pmax, 32));
    if (!__all(pmax - mr <= 8.0f)) {  // defer-max (THR=8)
      float nm = fmaxf(mr, pmax);
      float sc = __expf(mr - nm);
      mr = nm;
      lr *= sc;
#pragma unroll
      for (int cb = 0; cb < 8; ++cb)
#pragma unroll
        for (int r = 0; r < 16; ++r) acc[cb][r] *= sc;
    }
    float p[16];
    float sum = 0.f;
#pragma unroll
    for (int r = 0; r < 16; ++r) { p[r] = __expf(S[r] - mr); sum += p[r]; }
    sum += __shfl_xor(sum, 32);
    lr += sum;
    // ---- P -> per-wave LDS ----
#pragma unroll
    for (int g = 0; g < 4; ++g) {
      ushort4 pk;
      pk.x = f2b(p[g * 4 + 0]); pk.y = f2b(p[g * 4 + 1]);
      pk.z = f2b(p[g * 4 + 2]); pk.w = f2b(p[g * 4 + 3]);
      *reinterpret_cast<ushort4*>(&P_lds[w][q * 36 + g * 8 + hi * 4]) = pk;
    }
    // ---- PV: O[q][c] += P[q][k] V[k][c] ----
    bf16x8 pa[2];
#pragma unroll
    for (int ks = 0; ks < 2; ++ks)
      pa[ks] = *reinterpret_cast<const bf16x8*>(&P_lds[w][q * 36 + ks * 16 + hi * 8]);
    __builtin_amdgcn_s_setprio(1);
#pragma unroll
    for (int ks = 0; ks < 2; ++ks)
#pragma unroll
      for (int cb = 0; cb < 8; ++cb) {
        int c = cb * 32 + q;
        int chunk = (ks * 2 + hi) ^ ((q >> 1) & 3);
        bf16x8 vb = *reinterpret_cast<const bf16x8*>(&V_lds[cur][c * 32 + chunk * 8]);
        acc[cb] = MFMA32(pa[ks], vb, acc[cb], 0, 0, 0);
      }
    __builtin_amdgcn_s_setprio(0);
    asm volatile("s_waitcnt vmcnt(0)" ::: "memory");
    __syncthreads();
    cur ^= 1;
  }
  const int sb = s * 4 + b;
  size_t pbase = ((size_t)sb * 4096 + rowq) * 256;
#pragma unroll
  for (int cb = 0; cb < 8; ++cb)
#pragma unroll
    for (int g = 0; g < 4; ++g) {
      ushort4 o;
      o.x = f2b(acc[cb][g * 4 + 0]); o.y = f2b(acc[cb][g * 4 + 1]);
      o.z = f2b(acc[cb][g * 4 + 2]); o.w = f2b(acc[cb][g * 4 + 3]);
      *reinterpret_cast<ushort4*>(&part[pbase + cb * 32 + g * 8 + hi * 4]) = o;
    }
  if (hi == 0) {
    mpart[sb * 4096 + rowq] = mr;
    lpart[sb * 4096 + rowq] = lr;
  }
}

// ---------------------------------------------------------------------------
// Kernel 4: combine splits + residual epilogue
// ---------------------------------------------------------------------------
__global__ __launch_bounds__(256) void k_comb(
    const unsigned short* __restrict__ part, const float* __restrict__ mpart,
    const float* __restrict__ lpart, const float* __restrict__ feat,
    const float* __restrict__ alpha, float* __restrict__ out) {
  __shared__ float wgt[4][64];
  __shared__ float tile[64][261];
  const int nt = blockIdx.x, b = blockIdx.y;
  const int n0 = nt * 64;
  const int tid = threadIdx.x;
  if (tid < 64) {
    int qn = n0 + tid;
    float m[4], lv[4];
#pragma unroll
    for (int s = 0; s < 4; ++s) {
      m[s] = mpart[(s * 4 + b) * 4096 + qn];
      lv[s] = lpart[(s * 4 + b) * 4096 + qn];
    }
    float M = fmaxf(fmaxf(m[0], m[1]), fmaxf(m[2], m[3]));
    float e[4], L = 0.f;
#pragma unroll
    for (int s = 0; s < 4; ++s) { e[s] = __expf(m[s] - M); L += e[s] * lv[s]; }
    float inv = 1.0f / L;
#pragma unroll
    for (int s = 0; s < 4; ++s) wgt[s][tid] = e[s] * inv;
  }
  __syncthreads();
  const int row = tid >> 2;
  const int c0 = (tid & 3) * 64;
  float acc[64];
#pragma unroll
  for (int k = 0; k < 64; ++k) acc[k] = 0.f;
  for (int s = 0; s < 4; ++s) {
    float ww = wgt[s][row];
    const unsigned short* p = part + (((size_t)(s * 4 + b)) * 4096 + n0 + row) * 256 + c0;
#pragma unroll
    for (int ch = 0; ch < 8; ++ch) {
      bf16x8 v = *reinterpret_cast<const bf16x8*>(p + ch * 8);
#pragma unroll
      for (int j = 0; j < 8; ++j) acc[ch * 8 + j] += ww * (float)v[j];
    }
  }
#pragma unroll
  for (int k = 0; k < 64; ++k) tile[row][c0 + k] = acc[k];
  __syncthreads();
  const float av = alpha[0];
  const int j = tid & 15, cb = tid >> 4;
#pragma unroll
  for (int p = 0; p < 16; ++p) {
    int c = cb * 16 + p;
    size_t gbase = ((size_t)(b * 256 + c)) * 4096 + n0 + j * 4;
    float4 f4 = *reinterpret_cast<const float4*>(feat + gbase);
    float4 o;
    o.x = f4.x + av * tile[j * 4 + 0][c];
    o.y = f4.y + av * tile[j * 4 + 1][c];
    o.z = f4.z + av * tile[j * 4 + 2][c];
    o.w = f4.w + av * tile[j * 4 + 3][c];
    *reinterpret_cast<float4*>(out + gbase) = o;
  }
}

extern "C" void kernel_launch(void* const* d_in, const int* in_sizes, int n_in,
                              void* d_out, int out_size, void* d_ws, size_t ws_size,
                              hipStream_t stream) {
  const float* feat  = (const float*)d_in[0];
  const float* Wa    = (const float*)d_in[1];
  const float* ba    = (const float*)d_in[2];
  const float* Wb    = (const float*)d_in[3];
  const float* bb    = (const float*)d_in[4];
  const float* Wm    = (const float*)d_in[5];
  const float* bm    = (const float*)d_in[6];
  const float* gamma = (const float*)d_in[7];
  const float* beta  = (const float*)d_in[8];
  const float* rmean = (const float*)d_in[9];
  const float* rvar  = (const float*)d_in[10];
  const float* alpha = (const float*)d_in[11];
  float* out = (float*)d_out;
  char* ws = (char*)d_ws;
  unsigned short* Qb   = (unsigned short*)(ws);                       // [0,8M)
  unsigned short* Kb   = (unsigned short*)(ws + ((size_t)8 << 20));   // [8M,16M)
  unsigned short* Vb   = (unsigned short*)(ws + ((size_t)16 << 20));  // [16M,24M)
  unsigned short* XT   = (unsigned short*)(ws + ((size_t)24 << 20));  // [24M,32M)
  unsigned short* part = (unsigned short*)(ws + ((size_t)24 << 20));  // [24M,56M)
  unsigned short* W16  = (unsigned short*)(ws + ((size_t)56 << 20));  // 384K
  float* mpart = (float*)(ws + ((size_t)56 << 20) + 393216);
  float* lpart = (float*)(ws + ((size_t)56 << 20) + 393216 + 262144);

  k_wconv<<<dim3(32, 3), 256, 0, stream>>>(Wa, Wb, Wm, W16);
  k_transpose<<<dim3(64, 4, 4), 256, 0, stream>>>(feat, XT);
  k_qkv<<<dim3(32, 3, 4), 256, 0, stream>>>(XT, W16, ba, bb, bm, gamma, beta,
                                            rmean, rvar, Qb, Kb, Vb);
  k_attn<<<dim3(512), dim3(256), 0, stream>>>(Qb, Kb, Vb, part, mpart, lpart);
  k_comb<<<dim3(64, 4), 256, 0, stream>>>(part, mpart, lpart, feat, alpha, out);
}

// Round 5
// 136.115 us; speedup vs baseline: 4.4282x; 1.2990x over previous
//
#include <hip/hip_runtime.h>
#include <hip/hip_bf16.h>

typedef __bf16 bf16x8 __attribute__((ext_vector_type(8)));
typedef float f32x4 __attribute__((ext_vector_type(4)));
typedef float f32x16 __attribute__((ext_vector_type(16)));
typedef unsigned int u32;
typedef long long i64;

#define MFMA16 __builtin_amdgcn_mfma_f32_16x16x32_bf16
#define MFMA32F8 __builtin_amdgcn_mfma_f32_32x32x16_fp8_fp8

__device__ __forceinline__ unsigned short f2b(float f) {
  return __builtin_bit_cast(unsigned short, (__bf16)f);
}

// pack 4 floats -> 4 fp8 e4m3 bytes (ascending)
__device__ __forceinline__ u32 pk4(float a, float b, float c, float d) {
  int v = __builtin_amdgcn_cvt_pk_fp8_f32(a, b, 0, false);
  v = __builtin_amdgcn_cvt_pk_fp8_f32(c, d, v, true);
  return (u32)v;
}

__device__ __forceinline__ void gload_lds16(const void* g, void* l) {
  __builtin_amdgcn_global_load_lds(
      (const __attribute__((address_space(1))) unsigned int*)g,
      (__attribute__((address_space(3))) unsigned int*)l, 16, 0, 0);
}

// ---------------------------------------------------------------------------
// Kernel 1: z<4: XT[b][n][c] = (bf16) x[b][c][n] ; z==4: W fp32->bf16
// ---------------------------------------------------------------------------
__global__ __launch_bounds__(256) void k_prep(const float* __restrict__ x,
                                              unsigned short* __restrict__ xt,
                                              const float* __restrict__ Wa,
                                              const float* __restrict__ Wb,
                                              const float* __restrict__ Wm,
                                              unsigned short* __restrict__ W16) {
  const int tid = threadIdx.x;
  if (blockIdx.z == 4) {
    int bid2 = blockIdx.x + (blockIdx.y << 6);
    if (bid2 < 96) {
      int m = bid2 >> 5;
      const float* W = (m == 0) ? Wa : (m == 1) ? Wb : Wm;
      int i = ((bid2 & 31) * 256 + tid) * 8;
      float4 a = *reinterpret_cast<const float4*>(W + i);
      float4 b = *reinterpret_cast<const float4*>(W + i + 4);
      ushort4 lo, hi;
      lo.x = f2b(a.x); lo.y = f2b(a.y); lo.z = f2b(a.z); lo.w = f2b(a.w);
      hi.x = f2b(b.x); hi.y = f2b(b.y); hi.z = f2b(b.z); hi.w = f2b(b.w);
      unsigned short* dst = W16 + m * 65536 + i;
      *reinterpret_cast<ushort4*>(dst) = lo;
      *reinterpret_cast<ushort4*>(dst + 4) = hi;
    }
    return;
  }
  __shared__ float tile[64][65];
  const int nt = blockIdx.x, ct = blockIdx.y, b = blockIdx.z;
  const int j4 = (tid & 15) * 4, r0 = tid >> 4;
  const float* src = x + ((size_t)(b * 256 + ct * 64) * 4096) + nt * 64;
#pragma unroll
  for (int p = 0; p < 4; ++p) {
    int r = r0 + p * 16;
    float4 v = *reinterpret_cast<const float4*>(src + (size_t)r * 4096 + j4);
    tile[r][j4] = v.x; tile[r][j4 + 1] = v.y; tile[r][j4 + 2] = v.z; tile[r][j4 + 3] = v.w;
  }
  __syncthreads();
  unsigned short* dst = xt + ((size_t)(b * 4096 + nt * 64)) * 256 + ct * 64;
#pragma unroll
  for (int p = 0; p < 4; ++p) {
    int r = r0 + p * 16;
    ushort4 o;
    o.x = f2b(tile[j4][r]);
    o.y = f2b(tile[j4 + 1][r]);
    o.z = f2b(tile[j4 + 2][r]);
    o.w = f2b(tile[j4 + 3][r]);
    *reinterpret_cast<ushort4*>(dst + (size_t)r * 256 + j4) = o;
  }
}

// ---------------------------------------------------------------------------
// Kernel 2: projections. mode 0: Q bf16 [n][c]; mode 1: K fp8 [n][c]
//   (swapped MFMA so lanes hold consecutive c -> u32 fp8 stores);
//   mode 2: V fp8 blocked [k8][c][8] (+BN).
// ---------------------------------------------------------------------------
__global__ __launch_bounds__(256) void k_qkv(
    const unsigned short* __restrict__ xt, const unsigned short* __restrict__ W16,
    const float* __restrict__ ba, const float* __restrict__ bb,
    const float* __restrict__ bm, const float* __restrict__ gamma,
    const float* __restrict__ beta, const float* __restrict__ rmean,
    const float* __restrict__ rvar,
    unsigned short* __restrict__ Q, unsigned char* __restrict__ K8,
    unsigned char* __restrict__ V8) {
  const int nt = blockIdx.x, mode = blockIdx.y, b = blockIdx.z;
  const int tid = threadIdx.x, w = tid >> 6, l = tid & 63;
  const int li = l & 15, lk = l >> 4;
  const unsigned short* W = W16 + mode * 65536;
  bf16x8 af[2][8];
#pragma unroll
  for (int rs = 0; rs < 2; ++rs) {
    const int row = nt * 128 + w * 32 + rs * 16 + li;
    const unsigned short* arow = xt + ((size_t)b * 4096 + row) * 256;
#pragma unroll
    for (int kk = 0; kk < 8; ++kk)
      af[rs][kk] = *reinterpret_cast<const bf16x8*>(arow + kk * 32 + lk * 8);
  }
  f32x4 zero = {0.f, 0.f, 0.f, 0.f};
  f32x4 acc[2][16];
#pragma unroll
  for (int rs = 0; rs < 2; ++rs)
#pragma unroll
    for (int i = 0; i < 16; ++i) acc[rs][i] = zero;
  if (mode == 1) {
    // swapped: D[row=c][col=n]
#pragma unroll
    for (int kk = 0; kk < 8; ++kk) {
#pragma unroll
      for (int of = 0; of < 16; ++of) {
        bf16x8 bfv = *reinterpret_cast<const bf16x8*>(W + (size_t)(of * 16 + li) * 256 + kk * 32 + lk * 8);
        acc[0][of] = MFMA16(bfv, af[0][kk], acc[0][of], 0, 0, 0);
        acc[1][of] = MFMA16(bfv, af[1][kk], acc[1][of], 0, 0, 0);
      }
    }
  } else {
#pragma unroll
    for (int kk = 0; kk < 8; ++kk) {
#pragma unroll
      for (int of = 0; of < 16; ++of) {
        bf16x8 bfv = *reinterpret_cast<const bf16x8*>(W + (size_t)(of * 16 + li) * 256 + kk * 32 + lk * 8);
        acc[0][of] = MFMA16(af[0][kk], bfv, acc[0][of], 0, 0, 0);
        acc[1][of] = MFMA16(af[1][kk], bfv, acc[1][of], 0, 0, 0);
      }
    }
  }
  if (mode == 0) {
#pragma unroll
    for (int rs = 0; rs < 2; ++rs) {
      unsigned short* out = Q + ((size_t)b * 4096 + nt * 128 + w * 32 + rs * 16) * 256;
#pragma unroll
      for (int of = 0; of < 16; ++of) {
        int c = of * 16 + li;
        float bs = ba[c];
#pragma unroll
        for (int r = 0; r < 4; ++r)
          out[(size_t)(lk * 4 + r) * 256 + c] = f2b(acc[rs][of][r] + bs);
      }
    }
  } else if (mode == 1) {
    // lane holds 4 consecutive c = of*16 + lk*4 + r for one n
#pragma unroll
    for (int rs = 0; rs < 2; ++rs) {
      const int n = nt * 128 + w * 32 + rs * 16 + li;
      unsigned char* out = K8 + ((size_t)b * 4096 + n) * 256;
#pragma unroll
      for (int of = 0; of < 16; ++of) {
        int c0 = of * 16 + lk * 4;
        float4 bs = *reinterpret_cast<const float4*>(bb + c0);
        u32 v = pk4(acc[rs][of][0] + bs.x, acc[rs][of][1] + bs.y,
                    acc[rs][of][2] + bs.z, acc[rs][of][3] + bs.w);
        *reinterpret_cast<u32*>(out + c0) = v;
      }
    }
  } else {
    // lane holds 4 consecutive n = n0..n0+3 for c = of*16+li
#pragma unroll
    for (int of = 0; of < 16; ++of) {
      int c = of * 16 + li;
      float g = rsqrtf(rvar[c] + 1e-5f) * gamma[c];
      float sh = (bm[c] - rmean[c]) * g + beta[c];
#pragma unroll
      for (int rs = 0; rs < 2; ++rs) {
        const int n0 = nt * 128 + w * 32 + rs * 16 + lk * 4;
        u32 v = pk4(acc[rs][of][0] * g + sh, acc[rs][of][1] * g + sh,
                    acc[rs][of][2] * g + sh, acc[rs][of][3] * g + sh);
        *reinterpret_cast<u32*>(V8 + (((size_t)b * 512 + (n0 >> 3)) * 256 + c) * 8 + (n0 & 7)) = v;
      }
    }
  }
}

// ---------------------------------------------------------------------------
// Kernel 3: fp8 flash attention, split-K. Grid 512 = 32 qt x 4 s x 4 b.
//   KVBLK=64, swapped-QK^T 32x32x16 fp8 MFMA, P in registers via
//   cvt_pk_fp8 + v_permlane32_swap, PV computes O^T (correct orientation).
// ---------------------------------------------------------------------------
__global__ __launch_bounds__(256, 2) void k_attn(
    const unsigned short* __restrict__ Q, const unsigned char* __restrict__ K8,
    const unsigned char* __restrict__ V8, unsigned short* __restrict__ part,
    float* __restrict__ mpart, float* __restrict__ lpart) {
  __shared__ unsigned char K_lds[2][64 * 256];      // [key][c] fp8, 16B-unit ^= key&7
  __shared__ unsigned char V_lds[2][8 * 256 * 8];   // [slab][c][8] fp8, linear
  const int bid = blockIdx.x;
  const int swz = (bid & 7) * 64 + (bid >> 3);  // XCD-contiguous, bijective
  const int qt = swz & 31;
  const int bs = swz >> 5;
  const int b = bs >> 2, s = bs & 3;
  const int tid = threadIdx.x, w = tid >> 6, l = tid & 63;
  const int q = l & 31, hi = l >> 5;
  const int rowq = qt * 128 + w * 32 + q;
  // Q -> fp8 register fragments (B-operand: lane=col rowq, k=c ascending)
  i64 qf[16];
  const unsigned short* qp = Q + ((size_t)b * 4096 + rowq) * 256 + hi * 8;
#pragma unroll
  for (int kk = 0; kk < 16; ++kk) {
    bf16x8 v = *reinterpret_cast<const bf16x8*>(qp + kk * 16);
    u32 lo = pk4((float)v[0], (float)v[1], (float)v[2], (float)v[3]);
    u32 hh = pk4((float)v[4], (float)v[5], (float)v[6], (float)v[7]);
    qf[kk] = (i64)(((unsigned long long)hh << 32) | lo);
  }
  f32x16 acc[8];
#pragma unroll
  for (int i = 0; i < 8; ++i)
#pragma unroll
    for (int r = 0; r < 16; ++r) acc[i][r] = 0.f;
  float mr = -3e38f, lr = 0.f;

  auto stageK = [&](int buf, int k0) {
#pragma unroll
    for (int g = 0; g < 4; ++g) {
      int row = w * 16 + g * 4 + (l >> 4);
      int c16 = (l & 15) ^ (row & 7);
      const unsigned char* src = K8 + ((size_t)b * 4096 + k0 + row) * 256 + c16 * 16;
      gload_lds16(src, &K_lds[buf][(w * 16 + g * 4) * 256]);
    }
  };
  auto stageV = [&](int buf, int k0) {
    const size_t k8b = (size_t)b * 512 + (k0 >> 3);
#pragma unroll
    for (int g = 0; g < 4; ++g) {
      int slab = w * 2 + (g >> 1);
      int pos = (g & 1) * 64 + l;
      const unsigned char* src = V8 + (k8b + slab) * 2048 + pos * 16;
      gload_lds16(src, &V_lds[buf][slab * 2048 + (g & 1) * 1024]);
    }
  };

  const int kbase = s * 1024;
  stageK(0, kbase);
  stageV(0, kbase);
  asm volatile("s_waitcnt vmcnt(0)" ::: "memory");
  __syncthreads();
  int cur = 0;
  for (int t = 0; t < 16; ++t) {
    if (t < 15) { stageK(cur ^ 1, kbase + (t + 1) * 64); stageV(cur ^ 1, kbase + (t + 1) * 64); }
    // ---- QK^T (swapped): S[key][q], two 32-key chunks ----
    f32x16 S0, S1;
#pragma unroll
    for (int r = 0; r < 16; ++r) { S0[r] = 0.f; S1[r] = 0.f; }
    __builtin_amdgcn_s_setprio(1);
#pragma unroll
    for (int kk = 0; kk < 16; ++kk) {
      int off = ((kk ^ (q & 7)) * 16) + hi * 8;
      i64 kf0 = *reinterpret_cast<const i64*>(&K_lds[cur][q * 256 + off]);
      i64 kf1 = *reinterpret_cast<const i64*>(&K_lds[cur][(32 + q) * 256 + off]);
      S0 = MFMA32F8(kf0, qf[kk], S0, 0, 0, 0);
      S1 = MFMA32F8(kf1, qf[kk], S1, 0, 0, 0);
    }
    __builtin_amdgcn_s_setprio(0);
    // ---- online softmax (lane holds 32 of 64 keys; partner lane^32 rest) ----
    float pmax = S0[0];
#pragma unroll
    for (int r = 1; r < 16; ++r) pmax = fmaxf(pmax, S0[r]);
#pragma unroll
    for (int r = 0; r < 16; ++r) pmax = fmaxf(pmax, S1[r]);
    pmax = fmaxf(pmax, __shfl_xor(pmax, 32));
    if (!__all(pmax - mr <= 5.0f)) {  // defer-max THR=5: p <= e^5 < fp8 max 448
      float nm = fmaxf(mr, pmax);
      float sc = __expf(mr - nm);
      mr = nm;
      lr *= sc;
#pragma unroll
      for (int cb = 0; cb < 8; ++cb)
#pragma unroll
        for (int r = 0; r < 16; ++r) acc[cb][r] *= sc;
    }
    float p0[16], p1[16];
    float sum = 0.f;
#pragma unroll
    for (int r = 0; r < 16; ++r) { p0[r] = __expf(S0[r] - mr); sum += p0[r]; }
#pragma unroll
    for (int r = 0; r < 16; ++r) { p1[r] = __expf(S1[r] - mr); sum += p1[r]; }
    sum += __shfl_xor(sum, 32);
    lr += sum;
    // ---- P -> fp8 A-frags in registers (cvt_pk + permlane32_swap) ----
    // lane holds P[q][key=(r&3)+4*hi+8*(r>>2)]; frag(ks) needs keys
    // ks*16 + hi*8 + 0..7 -> swap word pairs across lane^32.
    u32 wA = pk4(p0[0], p0[1], p0[2], p0[3]);
    u32 wB = pk4(p0[4], p0[5], p0[6], p0[7]);
    u32 wC = pk4(p0[8], p0[9], p0[10], p0[11]);
    u32 wD = pk4(p0[12], p0[13], p0[14], p0[15]);
    u32 wE = pk4(p1[0], p1[1], p1[2], p1[3]);
    u32 wF = pk4(p1[4], p1[5], p1[6], p1[7]);
    u32 wG = pk4(p1[8], p1[9], p1[10], p1[11]);
    u32 wH = pk4(p1[12], p1[13], p1[14], p1[15]);
    asm volatile("v_permlane32_swap_b32 %0, %1" : "+v"(wA), "+v"(wB));
    asm volatile("v_permlane32_swap_b32 %0, %1" : "+v"(wC), "+v"(wD));
    asm volatile("v_permlane32_swap_b32 %0, %1" : "+v"(wE), "+v"(wF));
    asm volatile("v_permlane32_swap_b32 %0, %1" : "+v"(wG), "+v"(wH));
    i64 pa0 = (i64)(((unsigned long long)wB << 32) | wA);
    i64 pa1 = (i64)(((unsigned long long)wD << 32) | wC);
    i64 pa2 = (i64)(((unsigned long long)wF << 32) | wE);
    i64 pa3 = (i64)(((unsigned long long)wH << 32) | wG);
    // ---- PV as O^T: acc[cb] holds O[q(rows via regs)][c = cb*32+q-lane] ----
    __builtin_amdgcn_s_setprio(1);
#pragma unroll
    for (int ks = 0; ks < 4; ++ks) {
      i64 pa = (ks == 0) ? pa0 : (ks == 1) ? pa1 : (ks == 2) ? pa2 : pa3;
      const int slab = ks * 2 + hi;
#pragma unroll
      for (int cb = 0; cb < 8; ++cb) {
        i64 vb = *reinterpret_cast<const i64*>(&V_lds[cur][slab * 2048 + (cb * 32 + q) * 8]);
        acc[cb] = MFMA32F8(vb, pa, acc[cb], 0, 0, 0);
      }
    }
    __builtin_amdgcn_s_setprio(0);
    asm volatile("s_waitcnt vmcnt(0)" ::: "memory");
    __syncthreads();
    cur ^= 1;
  }
  // ---- store partial: part[sb][rowq][c], c = cb*32 + (r&3) + 8*(r>>2) + 4*hi
  const int sb = s * 4 + b;
  size_t pbase = ((size_t)sb * 4096 + rowq) * 256;
#pragma unroll
  for (int cb = 0; cb < 8; ++cb)
#pragma unroll
    for (int g = 0; g < 4; ++g) {
      ushort4 o;
      o.x = f2b(acc[cb][g * 4 + 0]); o.y = f2b(acc[cb][g * 4 + 1]);
      o.z = f2b(acc[cb][g * 4 + 2]); o.w = f2b(acc[cb][g * 4 + 3]);
      *reinterpret_cast<ushort4*>(&part[pbase + cb * 32 + g * 8 + hi * 4]) = o;
    }
  if (hi == 0) {
    mpart[sb * 4096 + rowq] = mr;
    lpart[sb * 4096 + rowq] = lr;
  }
}

// ---------------------------------------------------------------------------
// Kernel 4: combine splits + residual epilogue
// ---------------------------------------------------------------------------
__global__ __launch_bounds__(256) void k_comb(
    const unsigned short* __restrict__ part, const float* __restrict__ mpart,
    const float* __restrict__ lpart, const float* __restrict__ feat,
    const float* __restrict__ alpha, float* __restrict__ out) {
  __shared__ float wgt[4][64];
  __shared__ float tile[64][261];
  const int nt = blockIdx.x, b = blockIdx.y;
  const int n0 = nt * 64;
  const int tid = threadIdx.x;
  if (tid < 64) {
    int qn = n0 + tid;
    float m[4], lv[4];
#pragma unroll
    for (int s = 0; s < 4; ++s) {
      m[s] = mpart[(s * 4 + b) * 4096 + qn];
      lv[s] = lpart[(s * 4 + b) * 4096 + qn];
    }
    float M = fmaxf(fmaxf(m[0], m[1]), fmaxf(m[2], m[3]));
    float e[4], L = 0.f;
#pragma unroll
    for (int s = 0; s < 4; ++s) { e[s] = __expf(m[s] - M); L += e[s] * lv[s]; }
    float inv = 1.0f / L;
#pragma unroll
    for (int s = 0; s < 4; ++s) wgt[s][tid] = e[s] * inv;
  }
  __syncthreads();
  const int row = tid >> 2;
  const int c0 = (tid & 3) * 64;
  float acc[64];
#pragma unroll
  for (int k = 0; k < 64; ++k) acc[k] = 0.f;
  for (int s = 0; s < 4; ++s) {
    float ww = wgt[s][row];
    const unsigned short* p = part + (((size_t)(s * 4 + b)) * 4096 + n0 + row) * 256 + c0;
#pragma unroll
    for (int ch = 0; ch < 8; ++ch) {
      bf16x8 v = *reinterpret_cast<const bf16x8*>(p + ch * 8);
#pragma unroll
      for (int j = 0; j < 8; ++j) acc[ch * 8 + j] += ww * (float)v[j];
    }
  }
#pragma unroll
  for (int k = 0; k < 64; ++k) tile[row][c0 + k] = acc[k];
  __syncthreads();
  const float av = alpha[0];
  const int j = tid & 15, cb = tid >> 4;
#pragma unroll
  for (int p = 0; p < 16; ++p) {
    int c = cb * 16 + p;
    size_t gbase = ((size_t)(b * 256 + c)) * 4096 + n0 + j * 4;
    float4 f4 = *reinterpret_cast<const float4*>(feat + gbase);
    float4 o;
    o.x = f4.x + av * tile[j * 4 + 0][c];
    o.y = f4.y + av * tile[j * 4 + 1][c];
    o.z = f4.z + av * tile[j * 4 + 2][c];
    o.w = f4.w + av * tile[j * 4 + 3][c];
    *reinterpret_cast<float4*>(out + gbase) = o;
  }
}

extern "C" void kernel_launch(void* const* d_in, const int* in_sizes, int n_in,
                              void* d_out, int out_size, void* d_ws, size_t ws_size,
                              hipStream_t stream) {
  const float* feat  = (const float*)d_in[0];
  const float* Wa    = (const float*)d_in[1];
  const float* ba    = (const float*)d_in[2];
  const float* Wb    = (const float*)d_in[3];
  const float* bb    = (const float*)d_in[4];
  const float* Wm    = (const float*)d_in[5];
  const float* bm    = (const float*)d_in[6];
  const float* gamma = (const float*)d_in[7];
  const float* beta  = (const float*)d_in[8];
  const float* rmean = (const float*)d_in[9];
  const float* rvar  = (const float*)d_in[10];
  const float* alpha = (const float*)d_in[11];
  float* out = (float*)d_out;
  char* ws = (char*)d_ws;
  unsigned short* Qb   = (unsigned short*)(ws);                       // [0,8M) bf16 [b][n][c]
  unsigned char*  K8   = (unsigned char*)(ws + ((size_t)8 << 20));    // [8M,12M) fp8 [b][n][c]
  unsigned char*  V8   = (unsigned char*)(ws + ((size_t)12 << 20));   // [12M,16M) fp8 [b][k8][c][8]
  unsigned short* XT   = (unsigned short*)(ws + ((size_t)16 << 20));  // [16M,24M) bf16
  unsigned short* part = (unsigned short*)(ws + ((size_t)24 << 20));  // [24M,56M) bf16
  unsigned short* W16  = (unsigned short*)(ws + ((size_t)56 << 20));  // 384K
  float* mpart = (float*)(ws + ((size_t)56 << 20) + 393216);
  float* lpart = (float*)(ws + ((size_t)56 << 20) + 393216 + 262144);

  k_prep<<<dim3(64, 4, 5), 256, 0, stream>>>(feat, XT, Wa, Wb, Wm, W16);
  k_qkv<<<dim3(32, 3, 4), 256, 0, stream>>>(XT, W16, ba, bb, bm, gamma, beta,
                                            rmean, rvar, Qb, K8, V8);
  k_attn<<<dim3(512), dim3(256), 0, stream>>>(Qb, K8, V8, part, mpart, lpart);
  k_comb<<<dim3(64, 4), 256, 0, stream>>>(part, mpart, lpart, feat, alpha, out);
}